// Round 12
// baseline (2120.856 us; speedup 1.0000x reference)
//
#include <hip/hip_runtime.h>
#include <math.h>

#define TT 1024
#define BB 64
#define II 128
#define HH 256
#define OO 128
#define GPB 16
#define NCOL 64
#define Z_STRIDE 392     // fallback kernel z stride
#define ZS2 264          // xW-path z strip stride (h only, padded)
#define PART_BG_STRIDE 68
#define PART_RC_STRIDE 273

// ws layout (both paths): abort @int 0; tagged hbuf [2][64][256] u64 @byte 16384.
// xW path additionally: xw [65536][1024] fp32 @byte 524288.
#define WS_HBUF_B 16384
#define WS_CLEAR_B (WS_HBUF_B + 2 * BB * HH * 8)
#define WS_XW_B   524288
#define WS_NEED   (524288ull + 268435456ull)

typedef unsigned long long u64;
typedef unsigned int u32;

__device__ __forceinline__ float rcp(float v) { return __builtin_amdgcn_rcpf(v); }
__device__ __forceinline__ float sigm(float v) { return rcp(1.f + __expf(-v)); }
__device__ __forceinline__ float ftanh(float v) {
    return __builtin_fmaf(-2.f, rcp(__expf(2.f * v) + 1.f), 1.f);
}
#define HLOAD(p) __hip_atomic_load((p), __ATOMIC_RELAXED, __HIP_MEMORY_SCOPE_AGENT)

// ============ xW = x @ W + bias  (parallel GEMM, 64x64 tiles) ============
extern "C" __global__ void __launch_bounds__(256) xw_gemm(
    const float* __restrict__ x, const float* __restrict__ W,
    const float* __restrict__ bias, float* __restrict__ xw)
{
    __shared__ float xs[64][65];
    __shared__ float wt[64][68];
    const int tid = threadIdx.x;
    const int tx = tid & 15, ty = tid >> 4;
    const int bm = blockIdx.x, bn = blockIdx.y;

    float acc[4][4];
#pragma unroll
    for (int i = 0; i < 4; ++i)
#pragma unroll
        for (int jj = 0; jj < 4; ++jj) acc[i][jj] = 0.f;

    for (int k0 = 0; k0 < 128; k0 += 64) {
#pragma unroll
        for (int l = 0; l < 4; ++l) {
            const int e = tid + l * 256;
            const int row = e >> 4, c4 = (e & 15) * 4;
            *(float4*)&xs[row][c4] =
                *(const float4*)(x + (size_t)(bm * 64 + row) * 128 + k0 + c4);
            *(float4*)&wt[row][c4] =
                *(const float4*)(W + (size_t)(k0 + row) * 1024 + bn * 64 + c4);
        }
        __syncthreads();
#pragma unroll 16
        for (int kk = 0; kk < 64; ++kk) {
            const float4 bv = *(const float4*)&wt[kk][tx * 4];
#pragma unroll
            for (int i = 0; i < 4; ++i) {
                const float av = xs[ty * 4 + i][kk];
                acc[i][0] += av * bv.x; acc[i][1] += av * bv.y;
                acc[i][2] += av * bv.z; acc[i][3] += av * bv.w;
            }
        }
        __syncthreads();
    }
#pragma unroll
    for (int i = 0; i < 4; ++i) {
        const int row = bm * 64 + ty * 4 + i, col = bn * 64 + tx * 4;
        float4 o;
        o.x = acc[i][0] + bias[col];
        o.y = acc[i][1] + bias[col + 1];
        o.z = acc[i][2] + bias[col + 2];
        o.w = acc[i][3] + bias[col + 3];
        *(float4*)(xw + (size_t)row * 1024 + col) = o;
    }
}

// ============ recurrent scan, xW-precomputed path ============
extern "C" __global__ void __launch_bounds__(256, 1) lstm_scan(
    const float* __restrict__ xw, const float* __restrict__ U,
    float* __restrict__ wsf)
{
    __shared__ float z[4 * ZS2];                 // h strips only
    __shared__ float part[16 * PART_RC_STRIDE];
    __shared__ int   misc[8];

    int* abortp = (int*)wsf;
    u64* hbuf   = (u64*)((char*)wsf + WS_HBUF_B);

    const int tid  = threadIdx.x;
    const int gid  = blockIdx.x & 15;
    const int p    = blockIdx.x >> 4;
    const int cg   = tid & 15;
    const int rc   = tid >> 4;
    const int lane = tid & 63;
    const int w    = tid >> 6;
    const int myb  = 4 * gid + w;
    const int j    = lane & 15;

    // U weights in VGPRs: wh[rrh][i][c] = U[rrh*64+rc*4+i][cg*4+c-mapped]
    float wh[4][4][4];
    {
        const int c0 = cg * 4;
        const int gcol = (c0 >> 4) * HH + p * 16 + (c0 & 15);
#pragma unroll
        for (int rrh = 0; rrh < 4; ++rrh)
#pragma unroll
            for (int i = 0; i < 4; ++i) {
                const int r = rrh * 64 + rc * 4 + i;
                const float4 wv = *(const float4*)(U + (size_t)r * 1024 + gcol);
                wh[rrh][i][0] = wv.x; wh[rrh][i][1] = wv.y;
                wh[rrh][i][2] = wv.z; wh[rrh][i][3] = wv.w;
            }
    }
    const int redcol = (lane >> 4) * HH + p * 16 + j;  // reduce thread's gate col
    float creg = 0.f;

    for (int idx = tid; idx < 4 * ZS2; idx += 256) z[idx] = 0.f;
    if (tid < 8) misc[tid] = 0;
    __syncthreads();

    // prefetch xw for step 1 (t index 0)
    float xwreg = xw[((size_t)myb * TT + 0) * 1024 + redcol];

    for (int t = 1; t <= TT; ++t) {
        // ---- staggered tagged poll: 2 load-sets in flight, detect == data
        if (t > 1) {
            const u32 want = (u32)(t - 1);
            const u64* hsrc = hbuf + ((size_t)((t - 1) & 1) * BB + myb) * HH;
            u64 n0, n1, n2, n3;
            u64 a0 = HLOAD(hsrc + lane),       a1 = HLOAD(hsrc + lane + 64),
                a2 = HLOAD(hsrc + lane + 128), a3 = HLOAD(hsrc + lane + 192);
            int it = 0, ab = 0;
            for (;;) {
                u64 b0 = HLOAD(hsrc + lane),       b1 = HLOAD(hsrc + lane + 64),
                    b2 = HLOAD(hsrc + lane + 128), b3 = HLOAD(hsrc + lane + 192);
                bool ok = ((u32)(a0 >> 32) == want) && ((u32)(a1 >> 32) == want)
                       && ((u32)(a2 >> 32) == want) && ((u32)(a3 >> 32) == want);
                if (__ballot(ok) == ~0ULL) { n0 = a0; n1 = a1; n2 = a2; n3 = a3; break; }
                a0 = HLOAD(hsrc + lane);       a1 = HLOAD(hsrc + lane + 64);
                a2 = HLOAD(hsrc + lane + 128); a3 = HLOAD(hsrc + lane + 192);
                ok = ((u32)(b0 >> 32) == want) && ((u32)(b1 >> 32) == want)
                  && ((u32)(b2 >> 32) == want) && ((u32)(b3 >> 32) == want);
                if (__ballot(ok) == ~0ULL) { n0 = b0; n1 = b1; n2 = b2; n3 = b3; break; }
                if ((++it & 63) == 0) {
                    int abv = HLOAD(abortp);
                    if (abv) { ab = 1; break; }
                    if (it > (1 << 19)) {
                        if (lane == 0)
                            __hip_atomic_store(abortp, 1, __ATOMIC_RELAXED,
                                               __HIP_MEMORY_SCOPE_AGENT);
                        ab = 1; break;
                    }
                }
            }
            if (ab) { if (lane == 0) misc[w] = 1; n0 = n1 = n2 = n3 = 0; }
            float* zdst = z + w * ZS2 + lane;
            zdst[0]   = __uint_as_float((u32)n0);
            zdst[64]  = __uint_as_float((u32)n1);
            zdst[128] = __uint_as_float((u32)n2);
            zdst[192] = __uint_as_float((u32)n3);
        }
        __syncthreads();                         // (1) z strips + part reuse safe
        if (misc[0] | misc[1] | misc[2] | misc[3]) break;

        // ---- h-matvec (256 rows)
        float acc[4][4];
#pragma unroll
        for (int a = 0; a < 4; ++a)
#pragma unroll
            for (int b = 0; b < 4; ++b) acc[a][b] = 0.f;
#pragma unroll
        for (int rrh = 0; rrh < 4; ++rrh) {
#pragma unroll
            for (int bg = 0; bg < 4; ++bg) {
                const float4 zv = *(const float4*)(z + bg * ZS2 + rrh * 64 + rc * 4);
#pragma unroll
                for (int c = 0; c < 4; ++c)
                    acc[bg][c] += zv.x * wh[rrh][0][c] + zv.y * wh[rrh][1][c]
                                + zv.z * wh[rrh][2][c] + zv.w * wh[rrh][3][c];
            }
        }
#pragma unroll
        for (int bg = 0; bg < 4; ++bg)
#pragma unroll
            for (int c = 0; c < 4; ++c)
                part[rc * PART_RC_STRIDE + bg * PART_BG_STRIDE + cg * 4 + c] = acc[bg][c];
        __syncthreads();                         // (2) partials visible, z reads done

        // ---- per-wave reduce + xw + shfl gates + tagged publish
        float s = xwreg;
#pragma unroll
        for (int r2 = 0; r2 < 16; ++r2)
            s += part[r2 * PART_RC_STRIDE + w * PART_BG_STRIDE + lane];

        const float sf = __shfl(s, j + 16);
        const float sg = __shfl(s, j + 32);
        const float so = __shfl(s, j + 48);
        if (lane < 16) {
            const float iv = sigm(s);
            const float fv = sigm(sf);
            const float gv = ftanh(sg);
            const float ov = sigm(so);
            creg = fv * creg + iv * gv;
            const float hv = ov * ftanh(creg);
            const u64 pk = ((u64)(u32)t << 32) | (u64)__float_as_uint(hv);
            __hip_atomic_store(
                hbuf + ((size_t)(t & 1) * BB + myb) * HH + p * 16 + j,
                pk, __ATOMIC_RELAXED, __HIP_MEMORY_SCOPE_AGENT);
        }
        // prefetch next step's xw (hidden under poll + h-dot of t+1)
        if (t < TT)
            xwreg = xw[((size_t)myb * TT + t) * 1024 + redcol];
    }
}

// ============ fallback: r11 kernel (x-dot in loop), used if ws too small ======
extern "C" __global__ void __launch_bounds__(256, 1) lstm_scan_fb(
    const float* __restrict__ x, const float* __restrict__ W,
    const float* __restrict__ U, const float* __restrict__ bias,
    float* __restrict__ wsf)
{
    __shared__ float z[4 * Z_STRIDE];
    __shared__ float part[16 * PART_RC_STRIDE];
    __shared__ int   misc[8];

    int* abortp = (int*)wsf;
    u64* hbuf   = (u64*)((char*)wsf + WS_HBUF_B);

    const int tid  = threadIdx.x;
    const int gid  = blockIdx.x & 15;
    const int p    = blockIdx.x >> 4;
    const int cg   = tid & 15;
    const int rc   = tid >> 4;
    const int lane = tid & 63;
    const int w    = tid >> 6;
    const int myb  = 4 * gid + w;
    const int j    = lane & 15;

    float wr[6][4][4];
    {
        const int c0 = cg * 4;
        const int gcol = (c0 >> 4) * HH + p * 16 + (c0 & 15);
#pragma unroll
        for (int rr = 0; rr < 6; ++rr)
#pragma unroll
            for (int i = 0; i < 4; ++i) {
                const int r = rr * 64 + rc * 4 + i;
                const float4 wv = (rr < 2)
                    ? *(const float4*)(W + (size_t)r * 1024 + gcol)
                    : *(const float4*)(U + (size_t)(r - II) * 1024 + gcol);
                wr[rr][i][0] = wv.x; wr[rr][i][1] = wv.y;
                wr[rr][i][2] = wv.z; wr[rr][i][3] = wv.w;
            }
    }
    const float bia_reg = bias[(lane >> 4) * HH + p * 16 + j];
    float creg = 0.f;

    for (int idx = tid; idx < 4 * Z_STRIDE; idx += 256) z[idx] = 0.f;
    if (tid < 8) misc[tid] = 0;
    if (tid < 128) {
        const int b2 = tid >> 5, l2 = tid & 31;
        const float4 xv = *(const float4*)(
            x + ((size_t)(4 * gid + b2) * TT + 0) * II + 4 * l2);
        *(float4*)(z + b2 * Z_STRIDE + 4 * l2) = xv;
    }
    __syncthreads();

    for (int t = 1; t <= TT; ++t) {
        float acc[4][4];
#pragma unroll
        for (int a = 0; a < 4; ++a)
#pragma unroll
            for (int b = 0; b < 4; ++b) acc[a][b] = 0.f;
#pragma unroll
        for (int rr = 0; rr < 2; ++rr)
#pragma unroll
            for (int bg = 0; bg < 4; ++bg) {
                const float4 zv = *(const float4*)(z + bg * Z_STRIDE + rr * 64 + rc * 4);
#pragma unroll
                for (int c = 0; c < 4; ++c)
                    acc[bg][c] += zv.x * wr[rr][0][c] + zv.y * wr[rr][1][c]
                                + zv.z * wr[rr][2][c] + zv.w * wr[rr][3][c];
            }

        if (t > 1) {
            const u32 want = (u32)(t - 1);
            const u64* hsrc = hbuf + ((size_t)((t - 1) & 1) * BB + myb) * HH;
            u64 n0, n1, n2, n3;
            int it = 0, ab = 0;
            for (;;) {
                n0 = HLOAD(hsrc + lane);       n1 = HLOAD(hsrc + lane + 64);
                n2 = HLOAD(hsrc + lane + 128); n3 = HLOAD(hsrc + lane + 192);
                const bool ok = ((u32)(n0 >> 32) == want) && ((u32)(n1 >> 32) == want)
                             && ((u32)(n2 >> 32) == want) && ((u32)(n3 >> 32) == want);
                if (__ballot(ok) == ~0ULL) break;
                if ((++it & 63) == 0) {
                    int abv = HLOAD(abortp);
                    if (abv) { ab = 1; break; }
                    if (it > (1 << 19)) {
                        if (lane == 0)
                            __hip_atomic_store(abortp, 1, __ATOMIC_RELAXED,
                                               __HIP_MEMORY_SCOPE_AGENT);
                        ab = 1; break;
                    }
                }
            }
            if (ab && lane == 0) misc[w] = 1;
            float* zdst = z + w * Z_STRIDE + II + lane;
            zdst[0]   = __uint_as_float((u32)n0);
            zdst[64]  = __uint_as_float((u32)n1);
            zdst[128] = __uint_as_float((u32)n2);
            zdst[192] = __uint_as_float((u32)n3);
        }
        __syncthreads();
        if (misc[0] | misc[1] | misc[2] | misc[3]) break;

#pragma unroll
        for (int rr = 2; rr < 6; ++rr)
#pragma unroll
            for (int bg = 0; bg < 4; ++bg) {
                const float4 zv = *(const float4*)(z + bg * Z_STRIDE + rr * 64 + rc * 4);
#pragma unroll
                for (int c = 0; c < 4; ++c)
                    acc[bg][c] += zv.x * wr[rr][0][c] + zv.y * wr[rr][1][c]
                                + zv.z * wr[rr][2][c] + zv.w * wr[rr][3][c];
            }
#pragma unroll
        for (int bg = 0; bg < 4; ++bg)
#pragma unroll
            for (int c = 0; c < 4; ++c)
                part[rc * PART_RC_STRIDE + bg * PART_BG_STRIDE + cg * 4 + c] = acc[bg][c];
        __syncthreads();

        float s = bia_reg;
#pragma unroll
        for (int r2 = 0; r2 < 16; ++r2)
            s += part[r2 * PART_RC_STRIDE + w * PART_BG_STRIDE + lane];

        const float sf = __shfl(s, j + 16);
        const float sg = __shfl(s, j + 32);
        const float so = __shfl(s, j + 48);
        if (lane < 16) {
            const float iv = sigm(s);
            const float fv = sigm(sf);
            const float gv = ftanh(sg);
            const float ov = sigm(so);
            creg = fv * creg + iv * gv;
            const float hv = ov * ftanh(creg);
            const u64 pk = ((u64)(u32)t << 32) | (u64)__float_as_uint(hv);
            __hip_atomic_store(
                hbuf + ((size_t)(t & 1) * BB + myb) * HH + p * 16 + j,
                pk, __ATOMIC_RELAXED, __HIP_MEMORY_SCOPE_AGENT);
        } else if (lane < 48 && t < TT) {
            const int l2 = lane - 16;
            const float4 xv = *(const float4*)(
                x + ((size_t)myb * TT + t) * II + 4 * l2);
            *(float4*)(z + w * Z_STRIDE + 4 * l2) = xv;
        }
        __syncthreads();
    }
}

extern "C" __global__ void __launch_bounds__(256) lstm_out(
    const float* __restrict__ wsf, const float* __restrict__ dw,
    const float* __restrict__ db, float* __restrict__ out)
{
    __shared__ float hs[256];
    __shared__ float red[256];
    const int b = blockIdx.x;
    const int tid = threadIdx.x;
    const u64* h0 = (const u64*)((const char*)wsf + WS_HBUF_B);  // parity 0 = h_1024
    hs[tid] = __uint_as_float((u32)h0[(size_t)b * HH + tid]);
    __syncthreads();
    const int o = tid & 127, half = tid >> 7;
    const float* wrow = dw + o * HH + half * 128;
    const float* hrow = hs + half * 128;
    float s = 0.f;
#pragma unroll
    for (int k = 0; k < 128; k += 4) {
        const float4 wv = *(const float4*)(wrow + k);
        s += hrow[k] * wv.x + hrow[k + 1] * wv.y + hrow[k + 2] * wv.z + hrow[k + 3] * wv.w;
    }
    red[tid] = s;
    __syncthreads();
    if (tid < 128)
        out[(size_t)b * OO + tid] = red[tid] + red[128 + tid] + db[tid];
}

extern "C" void kernel_launch(void* const* d_in, const int* in_sizes, int n_in,
                              void* d_out, int out_size, void* d_ws, size_t ws_size,
                              hipStream_t stream)
{
    const float* x    = (const float*)d_in[0];
    const float* W    = (const float*)d_in[1];
    const float* U    = (const float*)d_in[2];
    const float* bias = (const float*)d_in[3];
    const float* dw   = (const float*)d_in[4];
    const float* db   = (const float*)d_in[5];
    float* out = (float*)d_out;
    float* ws  = (float*)d_ws;

    hipMemsetAsync(d_ws, 0, WS_CLEAR_B, stream);
    if (ws_size >= WS_NEED) {
        float* xw = (float*)((char*)d_ws + WS_XW_B);
        hipLaunchKernelGGL(xw_gemm, dim3(1024, 16), dim3(256), 0, stream,
                           x, W, bias, xw);
        hipLaunchKernelGGL(lstm_scan, dim3(256), dim3(256), 0, stream,
                           xw, U, ws);
    } else {
        hipLaunchKernelGGL(lstm_scan_fb, dim3(256), dim3(256), 0, stream,
                           x, W, U, bias, ws);
    }
    hipLaunchKernelGGL(lstm_out, dim3(64), dim3(256), 0, stream, ws, dw, db, out);
}